// Round 6
// baseline (5999.333 us; speedup 1.0000x reference)
//
#include <hip/hip_runtime.h>
#include <hip/hip_bf16.h>

using bf16 = __hip_bfloat16;

__device__ inline float u2f(unsigned int u) { return __uint_as_float(u << 16); }
__device__ inline float toF(float x) { return x; }
__device__ inline float toF(bf16 x) { return __bfloat162float(x); }
__device__ inline void storeO(float* p, float v) { *p = v; }
__device__ inline void storeO(bf16* p, float v) { *p = __float2bfloat16(v); }

// ---------------------------------------------------------------- layernorm
__device__ inline float waveRedSum(float x) {
#pragma unroll
    for (int off = 32; off; off >>= 1) x += __shfl_xor(x, off, 64);
    return x;
}

// one block per row, D = 1024, 4 elems/thread. T = float or bf16 input.
template <typename T>
__global__ __launch_bounds__(256) void layernorm_k(const T* __restrict__ in,
                                                   const float* __restrict__ g,
                                                   const float* __restrict__ bta,
                                                   bf16* __restrict__ out) {
    const int row = blockIdx.x, t = threadIdx.x;
    const int lane = t & 63, wid = t >> 6;
    const T* xr = in + (size_t)row * 1024;
    float v0, v1, v2, v3;
    if constexpr (sizeof(T) == 4) {
        float4 u = ((const float4*)xr)[t];
        v0 = u.x; v1 = u.y; v2 = u.z; v3 = u.w;
    } else {
        ushort4 u = ((const ushort4*)xr)[t];
        v0 = u2f(u.x); v1 = u2f(u.y); v2 = u2f(u.z); v3 = u2f(u.w);
    }
    __shared__ float red[8];
    float s = waveRedSum(v0 + v1 + v2 + v3);
    if (lane == 0) red[wid] = s;
    __syncthreads();
    float mu = (red[0] + red[1] + red[2] + red[3]) * (1.f / 1024.f);
    float d0 = v0 - mu, d1 = v1 - mu, d2 = v2 - mu, d3 = v3 - mu;
    float ss = waveRedSum(d0 * d0 + d1 * d1 + d2 * d2 + d3 * d3);
    if (lane == 0) red[4 + wid] = ss;
    __syncthreads();
    float var = (red[4] + red[5] + red[6] + red[7]) * (1.f / 1024.f);
    float inv = rsqrtf(var + 1e-6f);
    const int c = t * 4;
    bf16* orow = out + (size_t)row * 1024;
    orow[c + 0] = __float2bfloat16(d0 * inv * g[c + 0] + bta[c + 0]);
    orow[c + 1] = __float2bfloat16(d1 * inv * g[c + 1] + bta[c + 1]);
    orow[c + 2] = __float2bfloat16(d2 * inv * g[c + 2] + bta[c + 2]);
    orow[c + 3] = __float2bfloat16(d3 * inv * g[c + 3] + bta[c + 3]);
}

// ---------------------------------------------------------------- VALU GEMM
// C[M,N] (OT = bf16 or float) = A[M,K] (bf16) @ B[K x N window, stride ldB] (fp32) + bias.
// 64x64 tile/block, 256 threads (16x16), 4x4 outputs/thread.
template <int GELU, int RES, int ACC, typename RT, typename OT>
__global__ __launch_bounds__(256) void vgemm_k(const bf16* __restrict__ A,
                                               const float* __restrict__ B, int ldB,
                                               const float* __restrict__ bias,
                                               const RT* __restrict__ resid,
                                               OT* C, int M, int N, int K) {
    __shared__ float As[32][64];   // [k][m]
    __shared__ float Bs[32][64];   // [k][n]
    const int tid = threadIdx.x;
    const int tx = tid & 15, ty = tid >> 4;
    const int m0 = blockIdx.y * 64, n0 = blockIdx.x * 64;
    const int ra = tid >> 2, ca8 = (tid & 3) * 8;
    const int kb8 = tid >> 3, nb8 = (tid & 7) * 8;
    float acc[4][4] = {};
    for (int k0 = 0; k0 < K; k0 += 32) {
        __syncthreads();
        const bf16* ap = A + (size_t)(m0 + ra) * K + k0 + ca8;
        const float* bp = B + (size_t)(k0 + kb8) * ldB + n0 + nb8;
#pragma unroll
        for (int j = 0; j < 8; ++j) As[ca8 + j][ra] = toF(ap[j]);
#pragma unroll
        for (int j = 0; j < 8; ++j) Bs[kb8][nb8 + j] = bp[j];
        __syncthreads();
#pragma unroll
        for (int kk = 0; kk < 32; ++kk) {
            float4 a4 = *(const float4*)(&As[kk][ty * 4]);
            float4 b4 = *(const float4*)(&Bs[kk][tx * 4]);
            float av[4] = {a4.x, a4.y, a4.z, a4.w};
            float bv[4] = {b4.x, b4.y, b4.z, b4.w};
#pragma unroll
            for (int i = 0; i < 4; ++i)
#pragma unroll
                for (int j = 0; j < 4; ++j) acc[i][j] += av[i] * bv[j];
        }
    }
#pragma unroll
    for (int i = 0; i < 4; ++i) {
        const int row = m0 + ty * 4 + i;
#pragma unroll
        for (int j = 0; j < 4; ++j) {
            const int col = n0 + tx * 4 + j;
            float val = acc[i][j] + (ACC ? 0.f : bias[col]);
            if (GELU) {
                float z = 0.7978845608028654f * (val + 0.044715f * val * val * val);
                float th = 1.f - 2.f / (__expf(2.f * z) + 1.f);
                val = 0.5f * val * (1.f + th);
            }
            const size_t idx = (size_t)row * N + col;
            if (RES) val += toF(resid[idx]);
            if (ACC) val += toF(C[idx]);
            storeO(&C[idx], val);
        }
    }
}

// ---------------------------------------------------------------- attention (brute force)
// One thread per (b, h, q-row). Two-pass softmax, K/V straight from global/L2.
// q,k,v,o: [8,1024,16,64] bf16.
__global__ __launch_bounds__(256) void attn_brute_k(const bf16* __restrict__ q,
                                                    const bf16* __restrict__ k,
                                                    const bf16* __restrict__ v,
                                                    bf16* __restrict__ o) {
    const int gid = blockIdx.x * 256 + threadIdx.x;     // [0, 131072)
    const int qi = gid & 1023, h = (gid >> 10) & 15, b = gid >> 14;
    const size_t qoff = (((size_t)b * 1024 + qi) * 16 + h) * 64;
    float Q[64];
#pragma unroll
    for (int d4 = 0; d4 < 16; ++d4) {
        ushort4 u = ((const ushort4*)(q + qoff))[d4];
        Q[d4 * 4 + 0] = u2f(u.x); Q[d4 * 4 + 1] = u2f(u.y);
        Q[d4 * 4 + 2] = u2f(u.z); Q[d4 * 4 + 3] = u2f(u.w);
    }
    float m = -1e30f;
    for (int j = 0; j <= qi; ++j) {
        const size_t koff = (((size_t)b * 1024 + j) * 16 + h) * 64;
        float s = 0.f;
#pragma unroll
        for (int d4 = 0; d4 < 16; ++d4) {
            ushort4 u = ((const ushort4*)(k + koff))[d4];
            s += Q[d4 * 4 + 0] * u2f(u.x) + Q[d4 * 4 + 1] * u2f(u.y)
               + Q[d4 * 4 + 2] * u2f(u.z) + Q[d4 * 4 + 3] * u2f(u.w);
        }
        m = fmaxf(m, s * 0.125f);
    }
    float l = 0.f, O[64];
#pragma unroll
    for (int d = 0; d < 64; ++d) O[d] = 0.f;
    for (int j = 0; j <= qi; ++j) {
        const size_t koff = (((size_t)b * 1024 + j) * 16 + h) * 64;
        float s = 0.f;
#pragma unroll
        for (int d4 = 0; d4 < 16; ++d4) {
            ushort4 u = ((const ushort4*)(k + koff))[d4];
            s += Q[d4 * 4 + 0] * u2f(u.x) + Q[d4 * 4 + 1] * u2f(u.y)
               + Q[d4 * 4 + 2] * u2f(u.z) + Q[d4 * 4 + 3] * u2f(u.w);
        }
        const float p = __expf(s * 0.125f - m);
        l += p;
#pragma unroll
        for (int d4 = 0; d4 < 16; ++d4) {
            ushort4 u = ((const ushort4*)(v + koff))[d4];
            O[d4 * 4 + 0] += p * u2f(u.x); O[d4 * 4 + 1] += p * u2f(u.y);
            O[d4 * 4 + 2] += p * u2f(u.z); O[d4 * 4 + 3] += p * u2f(u.w);
        }
    }
    const float invl = 1.f / l;
#pragma unroll
    for (int d = 0; d < 64; ++d) o[qoff + d] = __float2bfloat16(O[d] * invl);
}

// ---------------------------------------------------------------- launch
extern "C" void kernel_launch(void* const* d_in, const int* in_sizes, int n_in,
                              void* d_out, int out_size, void* d_ws, size_t ws_size,
                              hipStream_t stream) {
    (void)out_size; (void)ws_size;
    const float* x = (const float*)d_in[0];
    // mask (structural) may or may not occupy slot 1; detect via size.
    const int base = (n_in >= 18 && in_sizes[1] > 4096) ? 2 : 1;
    const float* ln1s = (const float*)d_in[base + 0];
    const float* ln1b = (const float*)d_in[base + 1];
    const float* wq   = (const float*)d_in[base + 2];
    const float* bq   = (const float*)d_in[base + 3];
    const float* wk   = (const float*)d_in[base + 4];
    const float* bk   = (const float*)d_in[base + 5];
    const float* wv   = (const float*)d_in[base + 6];
    const float* bv   = (const float*)d_in[base + 7];
    const float* wo   = (const float*)d_in[base + 8];
    const float* bo   = (const float*)d_in[base + 9];
    const float* ln2s = (const float*)d_in[base + 10];
    const float* ln2b = (const float*)d_in[base + 11];
    const float* w1   = (const float*)d_in[base + 12];
    const float* b1   = (const float*)d_in[base + 13];
    const float* w2   = (const float*)d_in[base + 14];
    const float* b2   = (const float*)d_in[base + 15];
    float* out = (float*)d_out;   // fp32 output (reference returns float32)

    // Workspace plan, peak 64MB, all lifetimes disjoint:
    //   [0,16)MB  h  (LN1 out; dead after V-GEMM)   -> ao (attn out)
    //   [16,32)MB qb (dead after attention)          -> x2
    //   [32,48)MB kb (dead after attention)          -> h2
    //   [48,64)MB vb (dead after attention)          -> f1c
    char* ws = (char*)d_ws;
    const size_t MB = 1u << 20;
    bf16* h   = (bf16*)(ws + 0 * MB);
    bf16* qb  = (bf16*)(ws + 16 * MB);
    bf16* kb  = (bf16*)(ws + 32 * MB);
    bf16* vb  = (bf16*)(ws + 48 * MB);
    bf16* ao  = (bf16*)(ws + 0 * MB);
    bf16* x2  = (bf16*)(ws + 16 * MB);
    bf16* h2  = (bf16*)(ws + 32 * MB);
    bf16* f1c = (bf16*)(ws + 48 * MB);

    const dim3 tb(256);
    const dim3 g64(16, 128);  // N=1024, M=8192 in 64x64 tiles

    layernorm_k<float><<<8192, tb, 0, stream>>>(x, ln1s, ln1b, h);
    vgemm_k<0, 0, 0, float, bf16><<<g64, tb, 0, stream>>>(h, wq, 1024, bq, nullptr, qb, 8192, 1024, 1024);
    vgemm_k<0, 0, 0, float, bf16><<<g64, tb, 0, stream>>>(h, wk, 1024, bk, nullptr, kb, 8192, 1024, 1024);
    vgemm_k<0, 0, 0, float, bf16><<<g64, tb, 0, stream>>>(h, wv, 1024, bv, nullptr, vb, 8192, 1024, 1024);
    attn_brute_k<<<512, tb, 0, stream>>>(qb, kb, vb, ao);
    vgemm_k<0, 1, 0, float, bf16><<<g64, tb, 0, stream>>>(ao, wo, 1024, bo, x, x2, 8192, 1024, 1024);
    layernorm_k<bf16><<<8192, tb, 0, stream>>>(x2, ln2s, ln2b, h2);
    // FFN chunked over D_FF: 4 slices of 1024; accumulate into fp32 out.
    for (int c = 0; c < 4; ++c) {
        vgemm_k<1, 0, 0, float, bf16><<<g64, tb, 0, stream>>>(
            h2, w1 + c * 1024, 4096, b1 + c * 1024, nullptr, f1c, 8192, 1024, 1024);
        if (c == 0)
            vgemm_k<0, 1, 0, bf16, float><<<g64, tb, 0, stream>>>(
                f1c, w2 + (size_t)c * 1024 * 1024, 1024, b2, x2, out, 8192, 1024, 1024);
        else
            vgemm_k<0, 0, 1, bf16, float><<<g64, tb, 0, stream>>>(
                f1c, w2 + (size_t)c * 1024 * 1024, 1024, nullptr, nullptr, out, 8192, 1024, 1024);
    }
}

// Round 7
// 1829.057 us; speedup vs baseline: 3.2800x; 3.2800x over previous
//
#include <hip/hip_runtime.h>
#include <hip/hip_bf16.h>

using bf16 = __hip_bfloat16;
typedef __attribute__((ext_vector_type(8))) short bf16x8;   // 8 bf16 = 4 VGPRs
typedef __attribute__((ext_vector_type(4))) float f32x4;

__device__ inline float u2f(unsigned int u) { return __uint_as_float(u << 16); }
__device__ inline float toF(float x) { return x; }
__device__ inline float toF(bf16 x) { return __bfloat162float(x); }
__device__ inline void storeO(float* p, float v) { *p = v; }
__device__ inline void storeO(bf16* p, float v) { *p = __float2bfloat16(v); }

// ---------------------------------------------------------------- transpose
// fp32 [R,C] -> bf16 [C,R]. R, C multiples of 32. block = 256 (32x8 logical).
__global__ __launch_bounds__(256) void transpose_k(const float* __restrict__ in,
                                                   bf16* __restrict__ out,
                                                   int R, int C) {
    __shared__ float tile[32][33];
    const int c0 = blockIdx.x * 32, r0 = blockIdx.y * 32;
    const int tx = threadIdx.x & 31, ty = threadIdx.x >> 5;
#pragma unroll
    for (int i = 0; i < 32; i += 8)
        tile[ty + i][tx] = in[(size_t)(r0 + ty + i) * C + (c0 + tx)];
    __syncthreads();
#pragma unroll
    for (int i = 0; i < 32; i += 8)
        out[(size_t)(c0 + ty + i) * R + (r0 + tx)] = __float2bfloat16(tile[tx][ty + i]);
}

// ---------------------------------------------------------------- layernorm
__device__ inline float waveRedSum(float x) {
#pragma unroll
    for (int off = 32; off; off >>= 1) x += __shfl_xor(x, off, 64);
    return x;
}

template <typename T>
__global__ __launch_bounds__(256) void layernorm_k(const T* __restrict__ in,
                                                   const float* __restrict__ g,
                                                   const float* __restrict__ bta,
                                                   bf16* __restrict__ out) {
    const int row = blockIdx.x, t = threadIdx.x;
    const int lane = t & 63, wid = t >> 6;
    const T* xr = in + (size_t)row * 1024;
    float v0, v1, v2, v3;
    if constexpr (sizeof(T) == 4) {
        float4 u = ((const float4*)xr)[t];
        v0 = u.x; v1 = u.y; v2 = u.z; v3 = u.w;
    } else {
        ushort4 u = ((const ushort4*)xr)[t];
        v0 = u2f(u.x); v1 = u2f(u.y); v2 = u2f(u.z); v3 = u2f(u.w);
    }
    __shared__ float red[8];
    float s = waveRedSum(v0 + v1 + v2 + v3);
    if (lane == 0) red[wid] = s;
    __syncthreads();
    float mu = (red[0] + red[1] + red[2] + red[3]) * (1.f / 1024.f);
    float d0 = v0 - mu, d1 = v1 - mu, d2 = v2 - mu, d3 = v3 - mu;
    float ss = waveRedSum(d0 * d0 + d1 * d1 + d2 * d2 + d3 * d3);
    if (lane == 0) red[4 + wid] = ss;
    __syncthreads();
    float var = (red[4] + red[5] + red[6] + red[7]) * (1.f / 1024.f);
    float inv = rsqrtf(var + 1e-6f);
    const int c = t * 4;
    bf16* orow = out + (size_t)row * 1024;
    orow[c + 0] = __float2bfloat16(d0 * inv * g[c + 0] + bta[c + 0]);
    orow[c + 1] = __float2bfloat16(d1 * inv * g[c + 1] + bta[c + 1]);
    orow[c + 2] = __float2bfloat16(d2 * inv * g[c + 2] + bta[c + 2]);
    orow[c + 3] = __float2bfloat16(d3 * inv * g[c + 3] + bta[c + 3]);
}

// ---------------------------------------------------------------- MFMA GEMM
// C[M,N] = A[M,K](bf16) @ B + bias. 128x128 tile/block, 256 thr = 2x2 waves
// of 64x64 (4x4 mfma_f32_16x16x32_bf16). LDS: As[m][32k], Bs[n][32k] bf16.
// BSRC=0: B fp32 [K,N] row-stride ldB (transpose-convert staged in-kernel).
// BSRC=1: B bf16 [N,K] row-stride ldB (pre-transposed; vector staged).
// Fragment mapping cross-validated (r2 vs r3 bit-identical results).
template <int BSRC, int GELU, int RES, int ACC, typename RT, typename OT>
__global__ __launch_bounds__(256) void mgemm_k(const bf16* __restrict__ A,
                                               const void* __restrict__ Bv, int ldB,
                                               const float* __restrict__ bias,
                                               const RT* __restrict__ resid,
                                               OT* C, int M, int N, int K) {
    __shared__ bf16 As[128 * 32];
    __shared__ bf16 Bs[128 * 32];
    const int tid = threadIdx.x;
    const int lane = tid & 63, wid = tid >> 6;
    const int l16 = lane & 15, quad = lane >> 4;
    const int wm = (wid >> 1) * 64, wn = (wid & 1) * 64;
    const int m0 = blockIdx.y * 128, n0 = blockIdx.x * 128;
    f32x4 acc[4][4] = {};
    for (int k0 = 0; k0 < K; k0 += 32) {
        __syncthreads();
        // stage A: 512 chunks of 8 bf16 (16B); thread does chunks tid, tid+256
#pragma unroll
        for (int p = 0; p < 2; ++p) {
            const int c = tid + p * 256;
            const int r = c >> 2, ch = (c & 3) * 8;
            *(uint4*)&As[r * 32 + ch] =
                *(const uint4*)(A + (size_t)(m0 + r) * K + k0 + ch);
        }
        if (BSRC == 0) {
            // B fp32 [K,N]: 1024 float4 chunks; transpose-convert into Bs[n][k]
            const float* B = (const float*)Bv;
#pragma unroll
            for (int p = 0; p < 4; ++p) {
                const int c = tid + p * 256;
                const int k = c >> 5, nc = (c & 31) * 4;
                float4 f = *(const float4*)(B + (size_t)(k0 + k) * ldB + n0 + nc);
                Bs[(nc + 0) * 32 + k] = __float2bfloat16(f.x);
                Bs[(nc + 1) * 32 + k] = __float2bfloat16(f.y);
                Bs[(nc + 2) * 32 + k] = __float2bfloat16(f.z);
                Bs[(nc + 3) * 32 + k] = __float2bfloat16(f.w);
            }
        } else {
            // B bf16 [N,K]: mirror of A staging
            const bf16* B = (const bf16*)Bv;
#pragma unroll
            for (int p = 0; p < 2; ++p) {
                const int c = tid + p * 256;
                const int r = c >> 2, ch = (c & 3) * 8;
                *(uint4*)&Bs[r * 32 + ch] =
                    *(const uint4*)(B + (size_t)(n0 + r) * ldB + k0 + ch);
            }
        }
        __syncthreads();
        bf16x8 a[4], b[4];
#pragma unroll
        for (int i = 0; i < 4; ++i)
            a[i] = *(const bf16x8*)&As[(wm + i * 16 + l16) * 32 + quad * 8];
#pragma unroll
        for (int i = 0; i < 4; ++i)
            b[i] = *(const bf16x8*)&Bs[(wn + i * 16 + l16) * 32 + quad * 8];
#pragma unroll
        for (int mi = 0; mi < 4; ++mi)
#pragma unroll
            for (int ni = 0; ni < 4; ++ni)
                acc[mi][ni] = __builtin_amdgcn_mfma_f32_16x16x32_bf16(
                    a[mi], b[ni], acc[mi][ni], 0, 0, 0);
    }
#pragma unroll
    for (int mi = 0; mi < 4; ++mi) {
#pragma unroll
        for (int ni = 0; ni < 4; ++ni) {
            const int col = n0 + wn + ni * 16 + l16;
            const float bv = ACC ? 0.f : bias[col];
#pragma unroll
            for (int r = 0; r < 4; ++r) {
                const int row = m0 + wm + mi * 16 + quad * 4 + r;
                float val = acc[mi][ni][r] + bv;
                if (GELU) {
                    float z = 0.7978845608028654f * (val + 0.044715f * val * val * val);
                    float th = 1.f - 2.f / (__expf(2.f * z) + 1.f);
                    val = 0.5f * val * (1.f + th);
                }
                const size_t idx = (size_t)row * N + col;
                if (RES) val += toF(resid[idx]);
                if (ACC) val += toF(C[idx]);
                storeO(&C[idx], val);
            }
        }
    }
}

// ---------------------------------------------------------------- attention
// q,k,v,o: [8,1024,16,64] bf16. One lane per q-row, online softmax; K/V tiles
// (64 rows) staged to LDS fp32. block = 256 = 4 waves = 256 q-rows.
// Same math as the validated brute-force version; LDS broadcast reads.
__global__ __launch_bounds__(256) void attn_k(const bf16* __restrict__ q,
                                              const bf16* __restrict__ k,
                                              const bf16* __restrict__ v,
                                              bf16* __restrict__ o) {
    const int b = blockIdx.z, h = blockIdx.y;
    const int qblock = blockIdx.x * 256;
    const int wave = threadIdx.x >> 6, lane = threadIdx.x & 63;
    const int qrow = qblock + wave * 64 + lane;
    __shared__ float Ks[64][64];
    __shared__ float Vs[64][64];
    float Q[64], O[64];
    float m = -1e30f, l = 0.f;
    const size_t qoff = (((size_t)b * 1024 + qrow) * 16 + h) * 64;
#pragma unroll
    for (int d4 = 0; d4 < 16; ++d4) {
        ushort4 u = ((const ushort4*)(q + qoff))[d4];
        Q[d4 * 4 + 0] = u2f(u.x); Q[d4 * 4 + 1] = u2f(u.y);
        Q[d4 * 4 + 2] = u2f(u.z); Q[d4 * 4 + 3] = u2f(u.w);
    }
#pragma unroll
    for (int d = 0; d < 64; ++d) O[d] = 0.f;

    const int ntiles = blockIdx.x * 4 + 4;
    for (int t = 0; t < ntiles; ++t) {
        const int j0 = t * 64;
        __syncthreads();
        {
            const int r = threadIdx.x >> 2, cbase = (threadIdx.x & 3) * 16;
            const size_t goff = (((size_t)b * 1024 + j0 + r) * 16 + h) * 64 + cbase;
            const ushort4* kp = (const ushort4*)(k + goff);
            const ushort4* vp = (const ushort4*)(v + goff);
#pragma unroll
            for (int i = 0; i < 4; ++i) {
                ushort4 ku = kp[i], vu = vp[i];
                const int c = cbase + i * 4;
                Ks[r][c + 0] = u2f(ku.x); Ks[r][c + 1] = u2f(ku.y);
                Ks[r][c + 2] = u2f(ku.z); Ks[r][c + 3] = u2f(ku.w);
                Vs[r][c + 0] = u2f(vu.x); Vs[r][c + 1] = u2f(vu.y);
                Vs[r][c + 2] = u2f(vu.z); Vs[r][c + 3] = u2f(vu.w);
            }
        }
        __syncthreads();
        int jend = qrow - j0 + 1;
        if (jend > 64) jend = 64;
        for (int jj = 0; jj < jend; ++jj) {
            float s0 = 0.f, s1 = 0.f, s2 = 0.f, s3 = 0.f;
#pragma unroll
            for (int d = 0; d < 64; d += 4) {
                s0 += Q[d + 0] * Ks[jj][d + 0];
                s1 += Q[d + 1] * Ks[jj][d + 1];
                s2 += Q[d + 2] * Ks[jj][d + 2];
                s3 += Q[d + 3] * Ks[jj][d + 3];
            }
            float s = ((s0 + s1) + (s2 + s3)) * 0.125f;
            if (s <= m) {
                float p = __expf(s - m);
                l += p;
#pragma unroll
                for (int d = 0; d < 64; ++d) O[d] += p * Vs[jj][d];
            } else {
                float scale = __expf(m - s);
                m = s;
                l = l * scale + 1.f;
#pragma unroll
                for (int d = 0; d < 64; ++d) O[d] = O[d] * scale + Vs[jj][d];
            }
        }
    }
    const float invl = 1.f / l;
#pragma unroll
    for (int d = 0; d < 64; ++d) o[qoff + d] = __float2bfloat16(O[d] * invl);
}

// ---------------------------------------------------------------- launch
extern "C" void kernel_launch(void* const* d_in, const int* in_sizes, int n_in,
                              void* d_out, int out_size, void* d_ws, size_t ws_size,
                              hipStream_t stream) {
    (void)out_size; (void)ws_size;
    const float* x = (const float*)d_in[0];
    const int base = (n_in >= 18 && in_sizes[1] > 4096) ? 2 : 1;  // skip mask
    const float* ln1s = (const float*)d_in[base + 0];
    const float* ln1b = (const float*)d_in[base + 1];
    const float* wq   = (const float*)d_in[base + 2];
    const float* bq   = (const float*)d_in[base + 3];
    const float* wk   = (const float*)d_in[base + 4];
    const float* bk   = (const float*)d_in[base + 5];
    const float* wv   = (const float*)d_in[base + 6];
    const float* bv   = (const float*)d_in[base + 7];
    const float* wo   = (const float*)d_in[base + 8];
    const float* bo   = (const float*)d_in[base + 9];
    const float* ln2s = (const float*)d_in[base + 10];
    const float* ln2b = (const float*)d_in[base + 11];
    const float* w1   = (const float*)d_in[base + 12];
    const float* b1   = (const float*)d_in[base + 13];
    const float* w2   = (const float*)d_in[base + 14];
    const float* b2   = (const float*)d_in[base + 15];
    float* out = (float*)d_out;   // fp32 output

    // Workspace (peak 64MB), phase-disjoint lifetimes:
    //   [0,16)   h (LN1)            -> ao (attn out)   -> f1c (FFN1 slice)
    //   [16,32)  qb                 -> x2 (residual2, live till end)
    //   [32,48)  kb                 -> h2 (LN2 out)
    //   [48,64)  vb                 -> w1T[48,56) + w2T[56,64)
    char* ws = (char*)d_ws;
    const size_t MB = 1u << 20;
    bf16* h   = (bf16*)(ws + 0 * MB);
    bf16* qb  = (bf16*)(ws + 16 * MB);
    bf16* kb  = (bf16*)(ws + 32 * MB);
    bf16* vb  = (bf16*)(ws + 48 * MB);
    bf16* ao  = (bf16*)(ws + 0 * MB);
    bf16* x2  = (bf16*)(ws + 16 * MB);
    bf16* h2  = (bf16*)(ws + 32 * MB);
    bf16* w1T = (bf16*)(ws + 48 * MB);   // [4096][1024] bf16, 8MB
    bf16* w2T = (bf16*)(ws + 56 * MB);   // [1024][4096] bf16, 8MB
    bf16* f1c = (bf16*)(ws + 0 * MB);

    const dim3 tb(256);
    const dim3 gD(8, 64);   // 1024/128, 8192/128

    layernorm_k<float><<<8192, tb, 0, stream>>>(x, ln1s, ln1b, h);
    mgemm_k<0, 0, 0, 0, float, bf16><<<gD, tb, 0, stream>>>(h, wq, 1024, bq, nullptr, qb, 8192, 1024, 1024);
    mgemm_k<0, 0, 0, 0, float, bf16><<<gD, tb, 0, stream>>>(h, wk, 1024, bk, nullptr, kb, 8192, 1024, 1024);
    mgemm_k<0, 0, 0, 0, float, bf16><<<gD, tb, 0, stream>>>(h, wv, 1024, bv, nullptr, vb, 8192, 1024, 1024);
    attn_k<<<dim3(4, 16, 8), tb, 0, stream>>>(qb, kb, vb, ao);
    // vb dead after attn: transpose FFN weights into [48,64)
    transpose_k<<<dim3(128, 32), tb, 0, stream>>>(w1, w1T, 1024, 4096);
    transpose_k<<<dim3(32, 128), tb, 0, stream>>>(w2, w2T, 4096, 1024);
    mgemm_k<0, 0, 1, 0, float, bf16><<<gD, tb, 0, stream>>>(ao, wo, 1024, bo, x, x2, 8192, 1024, 1024);
    layernorm_k<bf16><<<8192, tb, 0, stream>>>(x2, ln2s, ln2b, h2);
    // FFN chunked over D_FF: 4 slices of 1024; w1T rows / w2T k-columns
    for (int c = 0; c < 4; ++c) {
        mgemm_k<1, 1, 0, 0, float, bf16><<<gD, tb, 0, stream>>>(
            h2, w1T + (size_t)c * 1024 * 1024, 1024, b1 + c * 1024, nullptr, f1c, 8192, 1024, 1024);
        if (c == 0)
            mgemm_k<1, 0, 1, 0, bf16, float><<<gD, tb, 0, stream>>>(
                f1c, w2T + c * 1024, 4096, b2, x2, out, 8192, 1024, 1024);
        else
            mgemm_k<1, 0, 0, 1, bf16, float><<<gD, tb, 0, stream>>>(
                f1c, w2T + c * 1024, 4096, nullptr, nullptr, out, 8192, 1024, 1024);
    }
}